// Round 7
// baseline (945.129 us; speedup 1.0000x reference)
//
#include <hip/hip_runtime.h>

#define EPSV 1e-5f
#define BSH 10          // bucket shift: 1024 nodes per bucket
#define BSZ 1024

// bf16x2 helpers (bf16 = top 16 bits of fp32; element 2f = low half)
__device__ inline float blo(unsigned u) { return __uint_as_float(u << 16); }
__device__ inline float bhi(unsigned u) { return __uint_as_float(u & 0xFFFF0000u); }
__device__ inline unsigned rne16(float v) {
    unsigned u = __float_as_uint(v);
    return (u + 0x7FFFu + ((u >> 16) & 1u)) >> 16;
}
__device__ inline unsigned pk(float lo, float hi) {
    return (rne16(hi) << 16) | rne16(lo);
}

// ================= CSR build: multisplit, 1024-node buckets, 4B pairs ====

__global__ __launch_bounds__(256) void k_hist(const int* __restrict__ dst,
                                              int* __restrict__ bcount, int E) {
    __shared__ int hist[1024];
    int t = threadIdx.x;
#pragma unroll
    for (int i = 0; i < 4; i++) hist[t + 256 * i] = 0;
    __syncthreads();
    int e0 = blockIdx.x * 4096;
#pragma unroll
    for (int r = 0; r < 16; r++) {
        int e = e0 + r * 256 + t;
        if (e < E) atomicAdd(&hist[dst[e] >> BSH], 1);
    }
    __syncthreads();
#pragma unroll
    for (int i = 0; i < 4; i++) {
        int bk = t + 256 * i;
        int h = hist[bk];
        if (h) atomicAdd(&bcount[bk], h);
    }
}

__global__ __launch_bounds__(256) void k_bscan(const int* __restrict__ bcount,
                                               int* __restrict__ bstart,
                                               int* __restrict__ gcur, int NB) {
    int t = threadIdx.x;
    int base = t * 4;
    int c[4], s = 0;
#pragma unroll
    for (int i = 0; i < 4; i++) {
        c[i] = (base + i < NB) ? bcount[base + i] : 0;
        s += c[i];
    }
    __shared__ int ls[256];
    ls[t] = s;
    __syncthreads();
    for (int off = 1; off < 256; off <<= 1) {
        int x = (t >= off) ? ls[t - off] : 0;
        __syncthreads();
        ls[t] += x;
        __syncthreads();
    }
    int run = (t == 0) ? 0 : ls[t - 1];
#pragma unroll
    for (int i = 0; i < 4; i++) {
        bstart[base + i] = run;
        gcur[base + i] = run;
        run += c[i];
    }
    if (t == 255) bstart[1024] = ls[255];
}

// pack: (dst_local << 22) | src   (src < 2^22, dst_local < 1024)
__global__ __launch_bounds__(256) void k_split(const int* __restrict__ src,
                                               const int* __restrict__ dst,
                                               int* __restrict__ gcur,
                                               unsigned* __restrict__ pairs, int E) {
    __shared__ int hist[1024];   // reused as rank counters in pass 2
    __shared__ int gb[1024];
    int t = threadIdx.x;
    int e0 = blockIdx.x * 4096;
    int sreg[16], dreg[16];
#pragma unroll
    for (int i = 0; i < 4; i++) hist[t + 256 * i] = 0;
    __syncthreads();
#pragma unroll
    for (int r = 0; r < 16; r++) {
        int e = e0 + r * 256 + t;
        if (e < E) {
            sreg[r] = src[e];
            dreg[r] = dst[e];
            atomicAdd(&hist[dreg[r] >> BSH], 1);
        } else {
            dreg[r] = -1;
        }
    }
    __syncthreads();
#pragma unroll
    for (int i = 0; i < 4; i++) {
        int bk = t + 256 * i;
        int h = hist[bk];
        gb[bk] = h ? atomicAdd(&gcur[bk], h) : 0;
    }
    __syncthreads();
#pragma unroll
    for (int i = 0; i < 4; i++) hist[t + 256 * i] = 0;
    __syncthreads();
#pragma unroll
    for (int r = 0; r < 16; r++) {
        if (dreg[r] >= 0) {
            int bk = dreg[r] >> BSH;
            int rk = atomicAdd(&hist[bk], 1);
            pairs[gb[bk] + rk] = ((unsigned)(dreg[r] & (BSZ - 1)) << 22) |
                                 (unsigned)sreg[r];
        }
    }
}

// one block per 1024-node bucket
__global__ __launch_bounds__(256) void k_build(const unsigned* __restrict__ pairs,
                                               const int* __restrict__ bstart,
                                               int* __restrict__ rowptr,
                                               int* __restrict__ rowend,
                                               float* __restrict__ dinv,
                                               int* __restrict__ colidx, int N) {
    int bid = blockIdx.x, t = threadIdx.x;
    int n0 = bid << BSH;
    int e0 = bstart[bid], e1 = bstart[bid + 1];
    __shared__ int cnt[BSZ];
    __shared__ int cur[BSZ];
    __shared__ int ls[256];
#pragma unroll
    for (int i = 0; i < 4; i++) cnt[t + 256 * i] = 0;
    __syncthreads();
    for (int e = e0 + t; e < e1; e += 256)
        atomicAdd(&cnt[pairs[e] >> 22], 1);
    __syncthreads();
    int base4 = t * 4;
    int c[4], s = 0;
#pragma unroll
    for (int i = 0; i < 4; i++) { c[i] = cnt[base4 + i]; s += c[i]; }
    ls[t] = s;
    __syncthreads();
    for (int off = 1; off < 256; off <<= 1) {
        int x = (t >= off) ? ls[t - off] : 0;
        __syncthreads();
        ls[t] += x;
        __syncthreads();
    }
    int run = e0 + ((t == 0) ? 0 : ls[t - 1]);
#pragma unroll
    for (int i = 0; i < 4; i++) {
        int node = n0 + base4 + i;
        cur[base4 + i] = run;
        if (node < N) {
            rowptr[node] = run;
            rowend[node] = run + c[i];
            dinv[node] = rsqrtf((float)c[i] + 1.0f);
        }
        run += c[i];
    }
    __syncthreads();
    for (int e = e0 + t; e < e1; e += 256) {
        unsigned p = pairs[e];
        int r = atomicAdd(&cur[p >> 22], 1);
        colidx[r] = (int)(p & 0x3FFFFFu);
    }
}

// ================= network (bf16 hidden states) =================

// h0 = relu(x @ W_in + b_in) -> bf16x2; half-wave per node, lane = feat pair
__global__ __launch_bounds__(256) void k_input(const float* __restrict__ x,
                                               const float* __restrict__ Win,
                                               const float* __restrict__ bin,
                                               unsigned* __restrict__ h2, int N) {
    int i = blockIdx.x * 256 + threadIdx.x;
    int node = i >> 5, f = i & 31;
    if (node >= N) return;
    const float* xr = x + node * 12;
    float a0 = bin[2 * f], a1 = bin[2 * f + 1];
#pragma unroll
    for (int k = 0; k < 12; k++) {
        float xv = xr[k];
        a0 = fmaf(xv, Win[k * 64 + 2 * f], a0);
        a1 = fmaf(xv, Win[k * 64 + 2 * f + 1], a1);
    }
    h2[i] = pk(fmaxf(a0, 0.0f), fmaxf(a1, 0.0f));
}

// hl (bf16) <- (h @ W) * dinv[node]; wave per row, lane j = out feature j
// FIXED: full 64-feature row = 8 uint4 (kk < 8), w index to 63.
__global__ __launch_bounds__(256) void k_gemm(const float* __restrict__ W,
                                              const float* __restrict__ dinv,
                                              const unsigned* __restrict__ hin2,
                                              unsigned short* __restrict__ hl, int N) {
    int j = threadIdx.x & 63;
    float w[64];
#pragma unroll
    for (int k = 0; k < 64; k++) w[k] = W[k * 64 + j];
    int wave = (blockIdx.x * 256 + threadIdx.x) >> 6;
    int nw = (gridDim.x * 256) >> 6;
    for (int node = wave; node < N; node += nw) {
        const uint4* row = (const uint4*)(hin2 + node * 32);
        float acc = 0.0f;
#pragma unroll
        for (int kk = 0; kk < 8; kk++) {
            uint4 u = row[kk];
            acc = fmaf(blo(u.x), w[8 * kk + 0], acc);
            acc = fmaf(bhi(u.x), w[8 * kk + 1], acc);
            acc = fmaf(blo(u.y), w[8 * kk + 2], acc);
            acc = fmaf(bhi(u.y), w[8 * kk + 3], acc);
            acc = fmaf(blo(u.z), w[8 * kk + 4], acc);
            acc = fmaf(bhi(u.z), w[8 * kk + 5], acc);
            acc = fmaf(blo(u.w), w[8 * kk + 6], acc);
            acc = fmaf(bhi(u.w), w[8 * kk + 7], acc);
        }
        hl[node * 64 + j] = (unsigned short)rne16(acc * dinv[node]);
    }
}

// gather + bias -> bf16 out, fused BN partial stats. Persistent blocks.
__global__ __launch_bounds__(256) void k_agg(const int* __restrict__ rowptr,
                                             const int* __restrict__ rowend,
                                             const int* __restrict__ colidx,
                                             const float* __restrict__ dinv,
                                             const unsigned* __restrict__ hl2,
                                             const float* __restrict__ b,
                                             unsigned* __restrict__ out2,
                                             float* __restrict__ part, int N) {
    int t = threadIdx.x;
    int hw = t >> 5, f = t & 31;
    float2 bb = ((const float2*)b)[f];
    float s0 = 0.f, s1 = 0.f, q0 = 0.f, q1 = 0.f;
    for (int dbase = blockIdx.x * 8; dbase < N; dbase += gridDim.x * 8) {
        int d = dbase + hw;
        if (d < N) {
            int e0 = rowptr[d], e1 = rowend[d];
            unsigned us = hl2[d * 32 + f];
            float A0 = blo(us), A1 = bhi(us), B0 = 0.f, B1 = 0.f;
            float C0 = 0.f, C1 = 0.f, D0 = 0.f, D1 = 0.f;
            int e = e0;
            for (; e + 4 <= e1; e += 4) {
                int i0 = colidx[e], i1 = colidx[e + 1];
                int i2 = colidx[e + 2], i3 = colidx[e + 3];
                unsigned u0 = hl2[i0 * 32 + f], u1 = hl2[i1 * 32 + f];
                unsigned u2 = hl2[i2 * 32 + f], u3 = hl2[i3 * 32 + f];
                A0 += blo(u0); A1 += bhi(u0);
                B0 += blo(u1); B1 += bhi(u1);
                C0 += blo(u2); C1 += bhi(u2);
                D0 += blo(u3); D1 += bhi(u3);
            }
            for (; e < e1; ++e) {
                unsigned uu = hl2[colidx[e] * 32 + f];
                A0 += blo(uu); A1 += bhi(uu);
            }
            float o0 = (A0 + B0) + (C0 + D0);
            float o1 = (A1 + B1) + (C1 + D1);
            float dv = dinv[d];
            o0 = fmaf(o0, dv, bb.x);
            o1 = fmaf(o1, dv, bb.y);
            unsigned up = pk(o0, o1);
            out2[d * 32 + f] = up;
            float r0 = blo(up), r1 = bhi(up);
            s0 += r0; q0 = fmaf(r0, r0, q0);
            s1 += r1; q1 = fmaf(r1, r1, q1);
        }
    }
    __shared__ float rs[8][64];
    __shared__ float rq[8][64];
    rs[hw][2 * f] = s0; rs[hw][2 * f + 1] = s1;
    rq[hw][2 * f] = q0; rq[hw][2 * f + 1] = q1;
    __syncthreads();
    if (t < 128) {
        float acc = 0.f;
#pragma unroll
        for (int h = 0; h < 8; h++) acc += (t < 64) ? rs[h][t] : rq[h][t - 64];
        part[blockIdx.x * 128 + t] = acc;
    }
}

// reduce partials -> BN affine A,B (ab[0..63]=A, ab[64..127]=B)
__global__ __launch_bounds__(128) void k_red(const float* __restrict__ part,
                                             const float* __restrict__ gamma,
                                             const float* __restrict__ beta,
                                             float* __restrict__ ab, int nb, float invN) {
    int t = threadIdx.x;
    float a = 0.f, b2 = 0.f, c = 0.f, d = 0.f;
    for (int i = 0; i < nb; i += 4) {
        a += part[i * 128 + t];
        b2 += part[(i + 1) * 128 + t];
        c += part[(i + 2) * 128 + t];
        d += part[(i + 3) * 128 + t];
    }
    __shared__ float sm[128];
    sm[t] = (a + b2) + (c + d);
    __syncthreads();
    if (t < 64) {
        float mu = sm[t] * invN;
        float var = fmaf(-mu, mu, sm[t + 64] * invN);
        float A = rsqrtf(var + EPSV) * gamma[t];
        ab[t] = A;
        ab[64 + t] = fmaf(-mu, A, beta[t]);
    }
}

// in-place bf16 BN affine (+ optional relu)
__global__ __launch_bounds__(256) void k_norm(unsigned* __restrict__ h2,
                                              const float* __restrict__ ab,
                                              int total, int relu) {
    int i = blockIdx.x * 256 + threadIdx.x;
    if (i >= total) return;
    int f = i & 31;
    unsigned u = h2[i];
    float v0 = fmaf(blo(u), ab[2 * f], ab[64 + 2 * f]);
    float v1 = fmaf(bhi(u), ab[2 * f + 1], ab[65 + 2 * f]);
    if (relu) { v0 = fmaxf(v0, 0.0f); v1 = fmaxf(v1, 0.0f); }
    h2[i] = pk(v0, v1);
}

// classifier: out = relu(h@W1+b1) @ W2 + b2 (bf16 rows, FIXED kk<8)
__global__ __launch_bounds__(256) void k_cls(const unsigned* __restrict__ h2,
                                             const float* __restrict__ W1,
                                             const float* __restrict__ b1,
                                             const float* __restrict__ W2,
                                             const float* __restrict__ b2,
                                             float* __restrict__ out, int N) {
    int lane = threadIdx.x & 63;
    int half = lane >> 5, jj = lane & 31;
    float w[64];
#pragma unroll
    for (int k = 0; k < 64; k++) w[k] = W1[k * 32 + jj];
    float bj = b1[jj];
    float w20 = W2[jj * 2 + 0], w21 = W2[jj * 2 + 1];
    float b20 = b2[0], b21 = b2[1];
    int wave = (blockIdx.x * 256 + threadIdx.x) >> 6;
    int nw = (gridDim.x * 256) >> 6;
    for (int base = wave * 2; base < N; base += nw * 2) {
        int node = base + half;
        int vnode = node < N ? node : 0;
        const uint4* row = (const uint4*)(h2 + vnode * 32);
        float acc = bj;
#pragma unroll
        for (int kk = 0; kk < 8; kk++) {
            uint4 u = row[kk];
            acc = fmaf(blo(u.x), w[8 * kk + 0], acc);
            acc = fmaf(bhi(u.x), w[8 * kk + 1], acc);
            acc = fmaf(blo(u.y), w[8 * kk + 2], acc);
            acc = fmaf(bhi(u.y), w[8 * kk + 3], acc);
            acc = fmaf(blo(u.z), w[8 * kk + 4], acc);
            acc = fmaf(bhi(u.z), w[8 * kk + 5], acc);
            acc = fmaf(blo(u.w), w[8 * kk + 6], acc);
            acc = fmaf(bhi(u.w), w[8 * kk + 7], acc);
        }
        float hv = fmaxf(acc, 0.0f);
        float t0 = hv * w20, t1 = hv * w21;
#pragma unroll
        for (int m = 1; m <= 16; m <<= 1) {
            t0 += __shfl_xor(t0, m, 64);
            t1 += __shfl_xor(t1, m, 64);
        }
        if (jj == 0 && node < N) {
            ((float2*)out)[node] = make_float2(t0 + b20, t1 + b21);
        }
    }
}

extern "C" void kernel_launch(void* const* d_in, const int* in_sizes, int n_in,
                              void* d_out, int out_size, void* d_ws, size_t ws_size,
                              hipStream_t stream) {
    const float* x     = (const float*)d_in[0];
    const int*   ei    = (const int*)d_in[1];
    const float* Win   = (const float*)d_in[2];
    const float* bin   = (const float*)d_in[3];
    const float* Wg    = (const float*)d_in[4];
    const float* bg    = (const float*)d_in[5];
    const float* gamma = (const float*)d_in[6];
    const float* beta  = (const float*)d_in[7];
    const float* W1    = (const float*)d_in[8];
    const float* b1    = (const float*)d_in[9];
    const float* W2    = (const float*)d_in[10];
    const float* b2    = (const float*)d_in[11];
    float* out = (float*)d_out;

    int N = in_sizes[0] / 12;
    int E = in_sizes[1] / 2;
    const int* src = ei;
    const int* dst = ei + E;
    float invN = 1.0f / (float)N;
    int NB = (N + BSZ - 1) >> BSH;
    const int AGB = 1280;  // agg persistent blocks

    char* ws = (char*)d_ws;
    size_t szhin = ((size_t)N * 64 * 2 + 255) / 256 * 256;  // bf16 hidden
    size_t szE4  = ((size_t)E * 4 + 255) / 256 * 256;
    size_t szN4  = ((size_t)N * 4 + 255) / 256 * 256;

    size_t off = 0;
    unsigned* hin2     = (unsigned*)(ws + off); off += szhin;
    unsigned short* hl = (unsigned short*)(ws + off); off += szhin;
    int* colidx        = (int*)(ws + off); off += szE4;
    int* rowptr        = (int*)(ws + off); off += szN4;
    int* rowend        = (int*)(ws + off); off += szN4;
    float* dinv        = (float*)(ws + off); off += szN4;
    int* bcount        = (int*)(ws + off); off += 4096;
    int* bstart        = (int*)(ws + off); off += 8192;   // 1025 ints
    int* gcur          = (int*)(ws + off); off += 4096;
    float* part        = (float*)(ws + off); off += (size_t)AGB * 128 * 4;
    float* ab          = (float*)(ws + off); off += 512;

    // packed pairs (4B) alias [hin2 | hl] — consumed by k_build before k_input
    unsigned* pairs = (unsigned*)ws;
    size_t need = off;
    if (2 * szhin < (size_t)E * 4) {
        pairs = (unsigned*)(ws + off);
        need += (size_t)E * 4;
    }
    if (ws_size < need || NB > 1024 || N >= (1 << 22)) return;  // loud failure

    hipMemsetAsync(bcount, 0, 4096, stream);

    int EB = (E + 4095) / 4096;
    k_hist<<<EB, 256, 0, stream>>>(dst, bcount, E);
    k_bscan<<<1, 256, 0, stream>>>(bcount, bstart, gcur, NB);
    k_split<<<EB, 256, 0, stream>>>(src, dst, gcur, pairs, E);
    k_build<<<NB, 256, 0, stream>>>(pairs, bstart, rowptr, rowend, dinv, colidx, N);

    k_input<<<(N * 32 + 255) / 256, 256, 0, stream>>>(x, Win, bin, hin2, N);

    for (int i = 0; i < 3; i++) {
        k_gemm<<<1024, 256, 0, stream>>>(Wg + i * 64 * 64, dinv, hin2, hl, N);
        k_agg<<<AGB, 256, 0, stream>>>(rowptr, rowend, colidx, dinv,
                                       (const unsigned*)hl, bg + i * 64,
                                       hin2, part, N);
        k_red<<<1, 128, 0, stream>>>(part, gamma + i * 64, beta + i * 64, ab,
                                     AGB, invN);
        k_norm<<<(N * 32 + 255) / 256, 256, 0, stream>>>(hin2, ab, N * 32,
                                                         (i < 2) ? 1 : 0);
    }
    k_cls<<<1024, 256, 0, stream>>>(hin2, W1, b1, W2, b2, out, N);
}

// Round 8
// 680.957 us; speedup vs baseline: 1.3879x; 1.3879x over previous
//
#include <hip/hip_runtime.h>

#define EPSV 1e-5f
#define BSH 8           // bucket shift: 256 nodes per bucket
#define BSZ 256

// bf16x2 helpers (bf16 = top 16 bits of fp32; element 2f = low half)
__device__ inline float blo(unsigned u) { return __uint_as_float(u << 16); }
__device__ inline float bhi(unsigned u) { return __uint_as_float(u & 0xFFFF0000u); }
__device__ inline unsigned rne16(float v) {
    unsigned u = __float_as_uint(v);
    return (u + 0x7FFFu + ((u >> 16) & 1u)) >> 16;
}
__device__ inline unsigned pk(float lo, float hi) {
    return (rne16(hi) << 16) | rne16(lo);
}

// ================= CSR build: multisplit, 256-node buckets, 4B pairs =====

__global__ __launch_bounds__(256) void k_hist(const int* __restrict__ dst,
                                              int* __restrict__ bcount, int E) {
    __shared__ int hist[1024];
    int t = threadIdx.x;
#pragma unroll
    for (int i = 0; i < 4; i++) hist[t + 256 * i] = 0;
    __syncthreads();
    int e0 = blockIdx.x * 4096;
#pragma unroll
    for (int r = 0; r < 16; r++) {
        int e = e0 + r * 256 + t;
        if (e < E) atomicAdd(&hist[dst[e] >> BSH], 1);
    }
    __syncthreads();
#pragma unroll
    for (int i = 0; i < 4; i++) {
        int bk = t + 256 * i;
        int h = hist[bk];
        if (h) atomicAdd(&bcount[bk], h);
    }
}

__global__ __launch_bounds__(256) void k_bscan(const int* __restrict__ bcount,
                                               int* __restrict__ bstart,
                                               int* __restrict__ gcur, int NB) {
    int t = threadIdx.x;
    int base = t * 4;
    int c[4], s = 0;
#pragma unroll
    for (int i = 0; i < 4; i++) {
        c[i] = (base + i < NB) ? bcount[base + i] : 0;
        s += c[i];
    }
    __shared__ int ls[256];
    ls[t] = s;
    __syncthreads();
    for (int off = 1; off < 256; off <<= 1) {
        int x = (t >= off) ? ls[t - off] : 0;
        __syncthreads();
        ls[t] += x;
        __syncthreads();
    }
    int run = (t == 0) ? 0 : ls[t - 1];
#pragma unroll
    for (int i = 0; i < 4; i++) {
        bstart[base + i] = run;
        gcur[base + i] = run;
        run += c[i];
    }
    if (t == 255) bstart[1024] = ls[255];
}

// pack: (dst_local << 22) | src   (src < 2^22, dst_local < 256)
__global__ __launch_bounds__(256) void k_split(const int* __restrict__ src,
                                               const int* __restrict__ dst,
                                               int* __restrict__ gcur,
                                               unsigned* __restrict__ pairs, int E) {
    __shared__ int hist[1024];   // reused as rank counters in pass 2
    __shared__ int gb[1024];
    int t = threadIdx.x;
    int e0 = blockIdx.x * 4096;
    int sreg[16], dreg[16];
#pragma unroll
    for (int i = 0; i < 4; i++) hist[t + 256 * i] = 0;
    __syncthreads();
#pragma unroll
    for (int r = 0; r < 16; r++) {
        int e = e0 + r * 256 + t;
        if (e < E) {
            sreg[r] = src[e];
            dreg[r] = dst[e];
            atomicAdd(&hist[dreg[r] >> BSH], 1);
        } else {
            dreg[r] = -1;
        }
    }
    __syncthreads();
#pragma unroll
    for (int i = 0; i < 4; i++) {
        int bk = t + 256 * i;
        int h = hist[bk];
        gb[bk] = h ? atomicAdd(&gcur[bk], h) : 0;
    }
    __syncthreads();
#pragma unroll
    for (int i = 0; i < 4; i++) hist[t + 256 * i] = 0;
    __syncthreads();
#pragma unroll
    for (int r = 0; r < 16; r++) {
        if (dreg[r] >= 0) {
            int bk = dreg[r] >> BSH;
            int rk = atomicAdd(&hist[bk], 1);
            pairs[gb[bk] + rk] = ((unsigned)(dreg[r] & (BSZ - 1)) << 22) |
                                 (unsigned)sreg[r];
        }
    }
}

// one block per 256-node bucket
__global__ __launch_bounds__(256) void k_build(const unsigned* __restrict__ pairs,
                                               const int* __restrict__ bstart,
                                               int* __restrict__ rowptr,
                                               int* __restrict__ rowend,
                                               float* __restrict__ dinv,
                                               int* __restrict__ colidx, int N) {
    int bid = blockIdx.x, t = threadIdx.x;
    int n0 = bid << BSH;
    int e0 = bstart[bid], e1 = bstart[bid + 1];
    __shared__ int cnt[256];
    __shared__ int ls[256];
    __shared__ int cur[256];
    cnt[t] = 0;
    __syncthreads();
    for (int e = e0 + t; e < e1; e += 256)
        atomicAdd(&cnt[pairs[e] >> 22], 1);
    __syncthreads();
    ls[t] = cnt[t];
    __syncthreads();
    for (int off = 1; off < 256; off <<= 1) {
        int x = (t >= off) ? ls[t - off] : 0;
        __syncthreads();
        ls[t] += x;
        __syncthreads();
    }
    int start = e0 + ((t == 0) ? 0 : ls[t - 1]);
    cur[t] = start;
    int node = n0 + t;
    if (node < N) {
        rowptr[node] = start;
        rowend[node] = start + cnt[t];
        dinv[node] = rsqrtf((float)cnt[t] + 1.0f);
    }
    __syncthreads();
    for (int e = e0 + t; e < e1; e += 256) {
        unsigned p = pairs[e];
        int r = atomicAdd(&cur[p >> 22], 1);
        colidx[r] = (int)(p & 0x3FFFFFu);
    }
}

// ================= network (bf16 hidden states) =================

// h0 = relu(x @ W_in + b_in) -> bf16x2; half-wave per node, lane = feat pair
__global__ __launch_bounds__(256) void k_input(const float* __restrict__ x,
                                               const float* __restrict__ Win,
                                               const float* __restrict__ bin,
                                               unsigned* __restrict__ h2, int N) {
    int i = blockIdx.x * 256 + threadIdx.x;
    int node = i >> 5, f = i & 31;
    if (node >= N) return;
    const float* xr = x + node * 12;
    float a0 = bin[2 * f], a1 = bin[2 * f + 1];
#pragma unroll
    for (int k = 0; k < 12; k++) {
        float xv = xr[k];
        a0 = fmaf(xv, Win[k * 64 + 2 * f], a0);
        a1 = fmaf(xv, Win[k * 64 + 2 * f + 1], a1);
    }
    h2[i] = pk(fmaxf(a0, 0.0f), fmaxf(a1, 0.0f));
}

// hl (bf16) <- (h @ W) * dinv[node]; wave per row, lane j = out feature j
__global__ __launch_bounds__(256) void k_gemm(const float* __restrict__ W,
                                              const float* __restrict__ dinv,
                                              const unsigned* __restrict__ hin2,
                                              unsigned short* __restrict__ hl, int N) {
    int j = threadIdx.x & 63;
    float w[64];
#pragma unroll
    for (int k = 0; k < 64; k++) w[k] = W[k * 64 + j];
    int wave = (blockIdx.x * 256 + threadIdx.x) >> 6;
    int nw = (gridDim.x * 256) >> 6;
    for (int node = wave; node < N; node += nw) {
        const uint4* row = (const uint4*)(hin2 + node * 32);
        float acc = 0.0f;
#pragma unroll
        for (int kk = 0; kk < 8; kk++) {
            uint4 u = row[kk];
            acc = fmaf(blo(u.x), w[8 * kk + 0], acc);
            acc = fmaf(bhi(u.x), w[8 * kk + 1], acc);
            acc = fmaf(blo(u.y), w[8 * kk + 2], acc);
            acc = fmaf(bhi(u.y), w[8 * kk + 3], acc);
            acc = fmaf(blo(u.z), w[8 * kk + 4], acc);
            acc = fmaf(bhi(u.z), w[8 * kk + 5], acc);
            acc = fmaf(blo(u.w), w[8 * kk + 6], acc);
            acc = fmaf(bhi(u.w), w[8 * kk + 7], acc);
        }
        hl[node * 64 + j] = (unsigned short)rne16(acc * dinv[node]);
    }
}

// gather: out[d] = bf16( dinv[d]*(hl[d] + sum_s hl[s]) + b )
// non-persistent: half-wave (32 lanes) per dst row, grid = N/8 blocks.
__global__ __launch_bounds__(256) void k_agg(const int* __restrict__ rowptr,
                                             const int* __restrict__ rowend,
                                             const int* __restrict__ colidx,
                                             const float* __restrict__ dinv,
                                             const unsigned* __restrict__ hl2,
                                             const float* __restrict__ b,
                                             unsigned* __restrict__ out2, int N) {
    int t = threadIdx.x;
    int hw = t >> 5, f = t & 31;
    int d = blockIdx.x * 8 + hw;
    if (d >= N) return;
    int e0 = rowptr[d], e1 = rowend[d];
    unsigned us = hl2[d * 32 + f];
    float a0 = blo(us), a1 = bhi(us);
    float b0 = 0.f, b1 = 0.f, c0 = 0.f, c1 = 0.f, g0 = 0.f, g1 = 0.f;
    int e = e0;
    for (; e + 4 <= e1; e += 4) {
        int s0 = colidx[e], s1 = colidx[e + 1], s2 = colidx[e + 2], s3 = colidx[e + 3];
        unsigned u0 = hl2[s0 * 32 + f], u1 = hl2[s1 * 32 + f];
        unsigned u2 = hl2[s2 * 32 + f], u3 = hl2[s3 * 32 + f];
        a0 += blo(u0); a1 += bhi(u0);
        b0 += blo(u1); b1 += bhi(u1);
        c0 += blo(u2); c1 += bhi(u2);
        g0 += blo(u3); g1 += bhi(u3);
    }
    for (; e < e1; ++e) {
        unsigned uu = hl2[colidx[e] * 32 + f];
        a0 += blo(uu); a1 += bhi(uu);
    }
    float acc0 = (a0 + b0) + (c0 + g0);
    float acc1 = (a1 + b1) + (c1 + g1);
    float dv = dinv[d];
    float o0 = fmaf(acc0, dv, b[2 * f]);
    float o1 = fmaf(acc1, dv, b[2 * f + 1]);
    out2[d * 32 + f] = pk(o0, o1);
}

// BN partial stats over bf16 h2 (per-block partials, deterministic)
__global__ __launch_bounds__(256) void k_stats(const unsigned* __restrict__ h2,
                                               float* __restrict__ part, int N) {
    int t = threadIdx.x;
    int hw = t >> 5, f = t & 31;
    float s0 = 0.f, s1 = 0.f, q0 = 0.f, q1 = 0.f;
    for (int node = blockIdx.x * 8 + hw; node < N; node += gridDim.x * 8) {
        unsigned u = h2[node * 32 + f];
        float r0 = blo(u), r1 = bhi(u);
        s0 += r0; q0 = fmaf(r0, r0, q0);
        s1 += r1; q1 = fmaf(r1, r1, q1);
    }
    __shared__ float rs[8][64];
    __shared__ float rq[8][64];
    rs[hw][2 * f] = s0; rs[hw][2 * f + 1] = s1;
    rq[hw][2 * f] = q0; rq[hw][2 * f + 1] = q1;
    __syncthreads();
    if (t < 128) {
        float acc = 0.f;
#pragma unroll
        for (int h = 0; h < 8; h++) acc += (t < 64) ? rs[h][t] : rq[h][t - 64];
        part[blockIdx.x * 128 + t] = acc;
    }
}

// reduce partials -> BN affine A,B (ab[0..63]=A, ab[64..127]=B)
__global__ __launch_bounds__(128) void k_red(const float* __restrict__ part,
                                             const float* __restrict__ gamma,
                                             const float* __restrict__ beta,
                                             float* __restrict__ ab, int nb, float invN) {
    int t = threadIdx.x;
    float a = 0.f, b2 = 0.f, c = 0.f, d = 0.f;
    for (int i = 0; i < nb; i += 4) {
        a += part[i * 128 + t];
        b2 += part[(i + 1) * 128 + t];
        c += part[(i + 2) * 128 + t];
        d += part[(i + 3) * 128 + t];
    }
    __shared__ float sm[128];
    sm[t] = (a + b2) + (c + d);
    __syncthreads();
    if (t < 64) {
        float mu = sm[t] * invN;
        float var = fmaf(-mu, mu, sm[t + 64] * invN);
        float A = rsqrtf(var + EPSV) * gamma[t];
        ab[t] = A;
        ab[64 + t] = fmaf(-mu, A, beta[t]);
    }
}

// in-place bf16 BN affine + relu (layers 0,1 only)
__global__ __launch_bounds__(256) void k_norm(unsigned* __restrict__ h2,
                                              const float* __restrict__ ab,
                                              int total) {
    int i = blockIdx.x * 256 + threadIdx.x;
    if (i >= total) return;
    int f = i & 31;
    unsigned u = h2[i];
    float v0 = fmaf(blo(u), ab[2 * f], ab[64 + 2 * f]);
    float v1 = fmaf(bhi(u), ab[2 * f + 1], ab[65 + 2 * f]);
    h2[i] = pk(fmaxf(v0, 0.0f), fmaxf(v1, 0.0f));
}

// classifier with BN2 affine folded into W1/b1 (no relu after BN2):
// out = relu((A*h+B)@W1 + b1) @ W2 + b2 = relu(h@(A*W1) + (b1 + B@W1)) ...
__global__ __launch_bounds__(256) void k_cls(const unsigned* __restrict__ h2,
                                             const float* __restrict__ ab,
                                             const float* __restrict__ W1,
                                             const float* __restrict__ b1,
                                             const float* __restrict__ W2,
                                             const float* __restrict__ b2,
                                             float* __restrict__ out, int N) {
    int lane = threadIdx.x & 63;
    int half = lane >> 5, jj = lane & 31;
    float w[64];
    float bj = b1[jj];
#pragma unroll
    for (int k = 0; k < 64; k++) {
        float w1 = W1[k * 32 + jj];
        w[k] = ab[k] * w1;
        bj = fmaf(ab[64 + k], w1, bj);
    }
    float w20 = W2[jj * 2 + 0], w21 = W2[jj * 2 + 1];
    float b20 = b2[0], b21 = b2[1];
    int wave = (blockIdx.x * 256 + threadIdx.x) >> 6;
    int nw = (gridDim.x * 256) >> 6;
    for (int base = wave * 2; base < N; base += nw * 2) {
        int node = base + half;
        int vnode = node < N ? node : 0;
        const uint4* row = (const uint4*)(h2 + vnode * 32);
        float acc = bj;
#pragma unroll
        for (int kk = 0; kk < 8; kk++) {
            uint4 u = row[kk];
            acc = fmaf(blo(u.x), w[8 * kk + 0], acc);
            acc = fmaf(bhi(u.x), w[8 * kk + 1], acc);
            acc = fmaf(blo(u.y), w[8 * kk + 2], acc);
            acc = fmaf(bhi(u.y), w[8 * kk + 3], acc);
            acc = fmaf(blo(u.z), w[8 * kk + 4], acc);
            acc = fmaf(bhi(u.z), w[8 * kk + 5], acc);
            acc = fmaf(blo(u.w), w[8 * kk + 6], acc);
            acc = fmaf(bhi(u.w), w[8 * kk + 7], acc);
        }
        float hv = fmaxf(acc, 0.0f);
        float t0 = hv * w20, t1 = hv * w21;
#pragma unroll
        for (int m = 1; m <= 16; m <<= 1) {
            t0 += __shfl_xor(t0, m, 64);
            t1 += __shfl_xor(t1, m, 64);
        }
        if (jj == 0 && node < N) {
            ((float2*)out)[node] = make_float2(t0 + b20, t1 + b21);
        }
    }
}

extern "C" void kernel_launch(void* const* d_in, const int* in_sizes, int n_in,
                              void* d_out, int out_size, void* d_ws, size_t ws_size,
                              hipStream_t stream) {
    const float* x     = (const float*)d_in[0];
    const int*   ei    = (const int*)d_in[1];
    const float* Win   = (const float*)d_in[2];
    const float* bin   = (const float*)d_in[3];
    const float* Wg    = (const float*)d_in[4];
    const float* bg    = (const float*)d_in[5];
    const float* gamma = (const float*)d_in[6];
    const float* beta  = (const float*)d_in[7];
    const float* W1    = (const float*)d_in[8];
    const float* b1    = (const float*)d_in[9];
    const float* W2    = (const float*)d_in[10];
    const float* b2    = (const float*)d_in[11];
    float* out = (float*)d_out;

    int N = in_sizes[0] / 12;
    int E = in_sizes[1] / 2;
    const int* src = ei;
    const int* dst = ei + E;
    float invN = 1.0f / (float)N;
    int NB = (N + BSZ - 1) >> BSH;
    const int SB = 104;  // stats partial blocks

    char* ws = (char*)d_ws;
    size_t szhin = ((size_t)N * 64 * 2 + 255) / 256 * 256;  // bf16 hidden
    size_t szE4  = ((size_t)E * 4 + 255) / 256 * 256;
    size_t szN4  = ((size_t)N * 4 + 255) / 256 * 256;

    size_t off = 0;
    unsigned* hin2     = (unsigned*)(ws + off); off += szhin;
    unsigned short* hl = (unsigned short*)(ws + off); off += szhin;
    int* colidx        = (int*)(ws + off); off += szE4;
    int* rowptr        = (int*)(ws + off); off += szN4;
    int* rowend        = (int*)(ws + off); off += szN4;
    float* dinv        = (float*)(ws + off); off += szN4;
    int* bcount        = (int*)(ws + off); off += 4096;
    int* bstart        = (int*)(ws + off); off += 8192;   // 1025 ints
    int* gcur          = (int*)(ws + off); off += 4096;
    float* part        = (float*)(ws + off); off += (size_t)SB * 128 * 4;
    float* ab          = (float*)(ws + off); off += 512;

    // packed pairs (4B) alias [hin2 | hl] — consumed by k_build before k_input
    unsigned* pairs = (unsigned*)ws;
    size_t need = off;
    if (2 * szhin < (size_t)E * 4) {
        pairs = (unsigned*)(ws + off);
        need += (size_t)E * 4;
    }
    if (ws_size < need || NB > 1024 || N >= (1 << 22)) return;  // loud failure

    hipMemsetAsync(bcount, 0, 4096, stream);

    int EB = (E + 4095) / 4096;
    k_hist<<<EB, 256, 0, stream>>>(dst, bcount, E);
    k_bscan<<<1, 256, 0, stream>>>(bcount, bstart, gcur, NB);
    k_split<<<EB, 256, 0, stream>>>(src, dst, gcur, pairs, E);
    k_build<<<NB, 256, 0, stream>>>(pairs, bstart, rowptr, rowend, dinv, colidx, N);

    k_input<<<(N * 32 + 255) / 256, 256, 0, stream>>>(x, Win, bin, hin2, N);

    for (int i = 0; i < 3; i++) {
        k_gemm<<<1024, 256, 0, stream>>>(Wg + i * 64 * 64, dinv, hin2, hl, N);
        k_agg<<<(N + 7) / 8, 256, 0, stream>>>(rowptr, rowend, colidx, dinv,
                                               (const unsigned*)hl, bg + i * 64,
                                               hin2, N);
        k_stats<<<SB, 256, 0, stream>>>(hin2, part, N);
        k_red<<<1, 128, 0, stream>>>(part, gamma + i * 64, beta + i * 64, ab,
                                     SB, invN);
        if (i < 2)
            k_norm<<<(N * 32 + 255) / 256, 256, 0, stream>>>(hin2, ab, N * 32);
    }
    k_cls<<<1024, 256, 0, stream>>>(hin2, ab, W1, b1, W2, b2, out, N);
}